// Round 8
// baseline (3348.362 us; speedup 1.0000x reference)
//
#include <hip/hip_runtime.h>
#include <hip/hip_bf16.h>

#define B_   128
#define T_   512
#define L_   8
#define E_   128
#define H_   512

// Partition: 8 batch-groups (16 rows each) x 16 WGs = 128 WGs, 512 thr each.
// gid = blockIdx % 8 -> one XCD per group under round-robin dispatch
// (runtime-verified by xcc vote; fallback to agent-scope protocol).
// Fast path: h/flag exchange via MUBUF sc0 on the XCD's coherent L2.
// Producers DUAL-PUBLISH (sc0 + sc1; vmcnt(1) -> fast flag; LLC drain
// deferred behind shadow). wave0-only poll, bounded spin, sleep each iter.
//
// THIS REVISION (vs R5-proven, which this restores structurally): 512-thr
// WGs, 8 waves at N=16 gate rows each (wave w: gate w&3, N-tile w>>2).
// bfrag halves to 80 VGPR -> compiler can pipeline ds_reads/x-loads; 2
// waves/SIMD hide latency. h-MFMA split into 2 acc chains (depth 8).
// Pointwise = R5's gbuf+barrier form: 1 cell/thread, 64B/row stores.
#define NG_   8
#define WPG_  16
#define JW_   32
#define GSTR  132
#define HBUFB 131072                 // bytes per fast h buffer (128 x 1024B)
#define HSU32 32768                  // u32 per slow h buffer
#define HSU64 16384                  // u64 per slow h buffer
#define BARSA_OFF (3 * HBUFB)        // fast flags offset within fast area
#define NFLG  128                    // per-wave flags per group (16 WG x 8)
#define FAST_BYTES (BARSA_OFF + NG_ * NFLG * 4)
#define SPIN_MAX 4096                // bounded fast poll

typedef __attribute__((ext_vector_type(8))) short s8v;      // 8 bf16
typedef __attribute__((ext_vector_type(4))) float f4v;      // MFMA acc
typedef __attribute__((ext_vector_type(4))) unsigned int u32x4;
typedef __attribute__((ext_vector_type(2))) unsigned int u32x2;
typedef unsigned long long u64;
typedef unsigned int u32;

__device__ __forceinline__ float bf16u_to_f(unsigned short s) {
  union { unsigned u; float f; } c; c.u = ((unsigned)s) << 16; return c.f;
}
// Agent-scope (sc1): LLC-coherent, bypasses non-coherent per-XCD L2.
__device__ __forceinline__ u64 llc_load8(const void* p) {
  return __hip_atomic_load((const u64*)p, __ATOMIC_RELAXED, __HIP_MEMORY_SCOPE_AGENT);
}
__device__ __forceinline__ unsigned llc_load4(const unsigned* p) {
  return __hip_atomic_load(p, __ATOMIC_RELAXED, __HIP_MEMORY_SCOPE_AGENT);
}
__device__ __forceinline__ void llc_store4(unsigned* p, unsigned v) {
  __hip_atomic_store(p, v, __ATOMIC_RELAXED, __HIP_MEMORY_SCOPE_AGENT);
}
// Fast activations via v_exp_f32 + v_rcp_f32 (~1e-6 abs err)
__device__ __forceinline__ float sigf(float x) {
  return __builtin_amdgcn_rcpf(1.f + __expf(-x));
}
__device__ __forceinline__ float tanh_f(float x) {
  return 1.f - 2.f * __builtin_amdgcn_rcpf(1.f + __expf(2.f * x));
}

// MUBUF sc0 ops (documented gfx950 cache flag for buffer_*).
__device__ __forceinline__ void buf_store_sc0(u32x4 srd, unsigned voff, unsigned v) {
  asm volatile("buffer_store_dword %0, %1, %2, 0 offen sc0"
               :: "v"(v), "v"(voff), "s"(srd) : "memory");
}
__device__ __forceinline__ void buf_store_sc0_x1(u32x4 srd, unsigned voff, unsigned v) {
  asm volatile("buffer_store_dword %0, %1, %2, 0 offen sc0"
               :: "v"(v), "v"(voff), "s"(srd) : "memory");
}
__device__ __forceinline__ u32x2 buf_load8_sc0(u32x4 srd, unsigned voff) {
  u32x2 v;
  asm volatile("buffer_load_dwordx2 %0, %1, %2, 0 offen sc0\n\ts_waitcnt vmcnt(0)"
               : "=v"(v) : "v"(voff), "s"(srd) : "memory");
  return v;
}

// Wave-0-only polls over 128 flags: lane l checks flags[2l],[2l+1].
__device__ __forceinline__ bool wait_flags_fast(u32x4 srd, unsigned polloff, unsigned tgt) {
  for (int it = 0; it < SPIN_MAX; ++it) {
    u32x2 v = buf_load8_sc0(srd, polloff);
    if (__all((int)(v[0] >= tgt && v[1] >= tgt))) return true;
    __builtin_amdgcn_s_sleep(1);
  }
  return false;
}
__device__ __forceinline__ void wait_flags_slow(const u32* flags, unsigned tgt) {
  const u32* p = flags + (threadIdx.x & 63) * 2;
  for (;;) {
    u64 v = llc_load8(p);
    if (__all((int)((u32)v >= tgt && (u32)(v >> 32) >= tgt))) return;
    __builtin_amdgcn_s_sleep(1);
  }
}

// ---------------------------------------------------------------------------
__global__ void embed_kernel(const int* __restrict__ tokens,
                             const float* __restrict__ values,
                             const float* __restrict__ emb,
                             __hip_bfloat16* __restrict__ x_bf) {
  int idx = blockIdx.x * blockDim.x + threadIdx.x;   // [0, B*T*E)
  int e  = idx & (E_ - 1);
  int bt = idx >> 7;
  int b  = bt >> 9;
  int t  = bt & (T_ - 1);
  const int*   tok = tokens + (size_t)bt * L_;
  const float* val = values + (size_t)bt * L_;
  float acc = 0.f;
#pragma unroll
  for (int l = 0; l < L_; ++l) acc += emb[(size_t)tok[l] * E_ + e] * val[l];
  acc = fmaxf(acc, 0.f);
  x_bf[((size_t)t * B_ + b) * E_ + e] = __float2bfloat16(acc);
}

// ---------------------------------------------------------------------------
// Fill: h_{t-1} group slab (16 rows x 512 bf16 = 16KB) -> LDS, xor-swizzled.
// 512 threads: thread tid covers 32B of row tid>>5. fast: 2x buffer dwordx4
// sc0 + one vmcnt(0). slow: 4x agent u64 loads.
__device__ __forceinline__ void fill_slab(u32x4* __restrict__ h_lds4, int mode,
                                          u32x4 srd, unsigned voffA,
                                          const u64* __restrict__ slow_src,
                                          int tid) {
  u32x4 c0, c1;
  if (mode == 0) {
    asm volatile(
        "buffer_load_dwordx4 %0, %2, %3, 0 offen sc0\n\t"
        "buffer_load_dwordx4 %1, %2, %3, 0 offen offset:16 sc0\n\t"
        "s_waitcnt vmcnt(0)"
        : "=&v"(c0), "=&v"(c1)
        : "v"(voffA), "s"(srd) : "memory");
  } else {
    u64 a, b;
    a = llc_load8(slow_src + 0); b = llc_load8(slow_src + 1);
    c0 = (u32x4){(u32)a, (u32)(a >> 32), (u32)b, (u32)(b >> 32)};
    a = llc_load8(slow_src + 2); b = llc_load8(slow_src + 3);
    c1 = (u32x4){(u32)a, (u32)(a >> 32), (u32)b, (u32)(b >> 32)};
  }
  const int row = tid >> 5;           // 0..15
  const int sw2 = row & 7;
  const int cb  = (tid & 31) * 2;     // 16B-chunk base within row (0..62)
  u32x4* dst = h_lds4 + (size_t)row * 64;
  dst[(cb + 0) ^ sw2] = c0;
  dst[(cb + 1) ^ sw2] = c1;
}

// ---------------------------------------------------------------------------
// out[b,t] = W_out . h_t + b_out from the LDS-staged (xor-swizzled) slab.
// Uses first 256 threads (16 rows x 16 lanes).
__device__ __forceinline__ void out_dot_lds16(const u32x4* __restrict__ h_lds4,
                                              int t, int gid,
                                              const float* __restrict__ wout_s,
                                              float bout, float* __restrict__ out) {
  if (threadIdx.x >= 256) return;
  const int um = threadIdx.x >> 4;
  const int uj = threadIdx.x & 15;
  const u64* row = (const u64*)(h_lds4 + (size_t)um * 64);
  const float* wr = wout_s + uj * 32;
  float p = 0.f;
#pragma unroll
  for (int j = 0; j < 4; ++j) {
    int pc = ((uj * 4 + j) ^ (um & 7)) * 2;
    u64 qa = row[pc], qb = row[pc + 1];
    p += bf16u_to_f((unsigned short)(qa      )) * wr[j * 8 + 0];
    p += bf16u_to_f((unsigned short)(qa >> 16)) * wr[j * 8 + 1];
    p += bf16u_to_f((unsigned short)(qa >> 32)) * wr[j * 8 + 2];
    p += bf16u_to_f((unsigned short)(qa >> 48)) * wr[j * 8 + 3];
    p += bf16u_to_f((unsigned short)(qb      )) * wr[j * 8 + 4];
    p += bf16u_to_f((unsigned short)(qb >> 16)) * wr[j * 8 + 5];
    p += bf16u_to_f((unsigned short)(qb >> 32)) * wr[j * 8 + 6];
    p += bf16u_to_f((unsigned short)(qb >> 48)) * wr[j * 8 + 7];
  }
  p += __shfl_down(p, 8, 16);
  p += __shfl_down(p, 4, 16);
  p += __shfl_down(p, 2, 16);
  p += __shfl_down(p, 1, 16);
  if (uj == 0) out[(size_t)(gid * 16 + um) * T_ + t] = p + bout;
}

// ---------------------------------------------------------------------------
__global__ void __launch_bounds__(512, 1)
lstm_kernel(const float* __restrict__ W_ih, const float* __restrict__ W_hh,
            const float* __restrict__ b_ih, const float* __restrict__ b_hh,
            const float* __restrict__ W_out, const float* __restrict__ b_out,
            const __hip_bfloat16* __restrict__ x_bf,
            u64* __restrict__ h_slow,             // 3 * B*H bf16 (zeroed), sc1 copies
            float* __restrict__ out,              // B*T f32
            u32* __restrict__ barsB,              // NG_ x 128 sc1 flags (zeroed)
            u32* __restrict__ xcc_tab,            // 128 slots (zeroed)
            char* __restrict__ fastbase) {        // sc0: 3 h bufs + flags (zeroed)
  __shared__ __align__(16) u32x4 h_lds4[16 * 64];  // 16 rows x 64 16B chunks
  __shared__ __align__(16) float gbuf[16][GSTR];   // gates staging
  __shared__ __align__(16) float bias_s[128];
  __shared__ float wout_s[H_];
  __shared__ int   cnt_same_s, bad_grp_s, mode_s;

  const int tid = threadIdx.x;
  const int wg  = blockIdx.x;
  const int gid = wg & (NG_ - 1);     // 0..7  (XCD under round-robin)
  const int g   = wg >> 3;            // 0..15
  const int j0g = g * JW_;

  const int w    = tid >> 6;          // wave 0..7: gate w&3, N-tile w>>2
  const int lane = tid & 63;
  const int m16  = lane & 15;
  const int q    = lane >> 4;
  const int sw   = m16 & 7;           // xor-swizzle key

  // SRD over the fast area (num_records=0xFFFFFFFF disables bounds check).
  u32x4 srd;
  {
    unsigned long long ba = (unsigned long long)fastbase;
    srd = (u32x4){(u32)ba, (u32)(ba >> 32) & 0xffffu, 0xffffffffu, 0x00020000u};
  }

  // ---- XCD-placement vote (one-time, agent scope; oracle-failure-safe) ---
  const unsigned xcc = (unsigned)__builtin_amdgcn_s_getreg(20 | (3 << 11));
  if (tid == 0) { cnt_same_s = 0; bad_grp_s = 0; llc_store4(xcc_tab + wg, xcc + 1u); }
  __syncthreads();
  if (tid < 128) {
    const u32* slot = xcc_tab + tid;
    unsigned v = llc_load4(slot);
    while (v == 0u) { __builtin_amdgcn_s_sleep(8); v = llc_load4(slot); }
    if (v == xcc + 1u) atomicAdd(&cnt_same_s, 1);
    else if ((tid & 7) == gid) bad_grp_s = 1;   // a group member is elsewhere
  }
  __syncthreads();
  if (tid == 0) mode_s = ((bad_grp_s == 0) && (cnt_same_s <= 64)) ? 0 : 1;

  // ---- one-time: W fragment (single N-tile of 16 rows, 20 K-steps) -------
  s8v bfrag[20];
  {
    const int gt = w & 3;
    const int r  = gt * H_ + j0g + (w >> 2) * 16 + m16;   // global gate row
    const float* wih_r = W_ih + (size_t)r * E_;
    const float* whh_r = W_hh + (size_t)r * H_;
#pragma unroll
    for (int ks = 0; ks < 20; ++ks) {
      s8v v;
#pragma unroll
      for (int i = 0; i < 8; ++i) {
        int k = ks * 32 + q * 8 + i;
        float ww = (k < E_) ? wih_r[k] : whh_r[k - E_];
        __hip_bfloat16 hb = __float2bfloat16(ww);
        v[i] = *(short*)&hb;
      }
      bfrag[ks] = v;
    }
  }
  if (tid < 128) {
    int gt = tid >> 5, jl = tid & 31;
    int r = gt * H_ + j0g + jl;
    bias_s[tid] = b_ih[r] + b_hh[r];
  }
  if (g == 0) for (int i = tid; i < H_; i += 512) wout_s[i] = W_out[i];

  // ---- per-step identities ----------------------------------------------
  const int um = tid >> 5;            // update row (0..15)
  const int j  = tid & 31;            // update unit within WG
  const int ub = gid * 16 + um;       // global batch row
  float cst = 0.f;
  const float bout = b_out[0];
  u32* h_slow32 = (u32*)h_slow;
  u32* flagsB   = barsB + gid * NFLG;
  u32* myflagB  = flagsB + g * 8 + w;
  const unsigned flagAoff   = (unsigned)(BARSA_OFF + (gid * NFLG + g * 8 + w) * 4);
  const unsigned polloff    = (unsigned)(BARSA_OFF + (gid * NFLG + lane * 2) * 4);
  const unsigned filloffA   = (unsigned)((gid * 16 + (tid >> 5)) * 1024 + (tid & 31) * 32);
  const unsigned slab_u64off = (unsigned)(gid * 16 * 128 + tid * 4);
  const unsigned hstoreA = (unsigned)(ub * 1024 + (j0g + j) * 2);      // even j only
  const unsigned hstoreS = (unsigned)(ub * 256 + ((j0g + j) >> 1));

  int rp = 2, wp = 0;                 // h_{-1}=zeros in buf2; h_t -> buf t%3
  f4v acc;

  // prologue: x-part of step 0 (M=16, single N-tile)
  {
    const __hip_bfloat16* ax0 = x_bf + (size_t)(gid * 16 + m16) * E_ + q * 8;
    acc = (f4v){0.f, 0.f, 0.f, 0.f};
#pragma unroll
    for (int ks = 0; ks < 4; ++ks) {
      s8v a0 = *(const s8v*)(ax0 + ks * 32);
      acc = __builtin_amdgcn_mfma_f32_16x16x32_bf16(a0, bfrag[ks], acc, 0, 0, 0);
    }
  }
  __syncthreads();   // bias/wout/mode_s ready

  for (int t = 0; t < T_; ++t) {
    // ---- wave 0 waits for step t-1 producers (bounded fast + fallback) --
    if (w == 0) {
      int m0 = mode_s;
      bool got = false;
      if (m0 == 0) {
        got = wait_flags_fast(srd, polloff, (unsigned)t);
        if (!got && lane == 0) mode_s = 1;   // permanent fallback
      }
      if (!got) wait_flags_slow(flagsB, (unsigned)t);
    }
    __syncthreads();   // release; also orders shadow h_lds reads before fill
    const int mode = mode_s;

    // ---- cooperative fill: h_{t-1} group slab -> LDS --------------------
    fill_slab(h_lds4, mode, srd, (unsigned)(rp * HBUFB) + filloffA,
              h_slow + (size_t)rp * HSU64 + slab_u64off, tid);
    __syncthreads();   // fill complete

    // ---- h-part MFMAs (K=512 from LDS; 2 acc chains, depth 8) -----------
    {
      const s8v* arow = (const s8v*)(h_lds4 + (size_t)m16 * 64);
      f4v acc2 = (f4v){0.f, 0.f, 0.f, 0.f};
#pragma unroll
      for (int ks4 = 0; ks4 < 16; ks4 += 2) {
        s8v a0 = arow[(ks4 * 4 + q) ^ sw];
        s8v a1 = arow[((ks4 + 1) * 4 + q) ^ sw];
        acc  = __builtin_amdgcn_mfma_f32_16x16x32_bf16(a0, bfrag[4 + ks4], acc, 0, 0, 0);
        acc2 = __builtin_amdgcn_mfma_f32_16x16x32_bf16(a1, bfrag[5 + ks4], acc2, 0, 0, 0);
      }
      acc[0] += acc2[0]; acc[1] += acc2[1]; acc[2] += acc2[2]; acc[3] += acc2[3];
    }

    // ---- stage gates to LDS (D: row=q*4+r, col=m16 within N-tile) -------
    {
      const int col = (w & 3) * 32 + (w >> 2) * 16 + m16;
#pragma unroll
      for (int r = 0; r < 4; ++r)
        gbuf[q * 4 + r][col] = acc[r];
    }
    __syncthreads();   // gates ready

    // ---- CRITICAL PATH: pointwise (1 cell/thread) -> dual store ---------
    {
      const float* gr = &gbuf[um][0];
      float ii = sigf(gr[j]      + bias_s[j]);
      float ff = sigf(gr[32 + j] + bias_s[32 + j]);
      float gg = tanh_f(gr[64 + j] + bias_s[64 + j]);
      float oo = sigf(gr[96 + j] + bias_s[96 + j]);
      cst = ff * cst + ii * gg;
      float h = oo * tanh_f(cst);
      __hip_bfloat16 hb = __float2bfloat16(h);
      unsigned short hu = *(unsigned short*)&hb;
      unsigned short pu = (unsigned short)__shfl_xor((int)hu, 1);
      if ((j & 1) == 0) {
        u32 wv = (u32)hu | ((u32)pu << 16);
        buf_store_sc0(srd, (unsigned)(wp * HBUFB) + hstoreA, wv);    // fast
        llc_store4(h_slow32 + (size_t)wp * HSU32 + hstoreS, wv);     // slow
      }
      // fast flag after the sc0 store acks at L2 (sc1 still outstanding)
      asm volatile("s_waitcnt vmcnt(1)" ::: "memory");
      if (lane == 0) buf_store_sc0_x1(srd, flagAoff, (unsigned)(t + 1));
    }

    // ---- poll-shadow work (other WGs are polling/filling) ---------------
    if (g == 0 && t > 0)               // h_{t-1} still staged in LDS
      out_dot_lds16(h_lds4, t - 1, gid, wout_s, bout, out);

    if (t + 1 < T_) {                  // x-part of step t+1
      const __hip_bfloat16* xt = x_bf + (size_t)(t + 1) * B_ * E_;
      const __hip_bfloat16* ax0 = xt + (size_t)(gid * 16 + m16) * E_ + q * 8;
      acc = (f4v){0.f, 0.f, 0.f, 0.f};
#pragma unroll
      for (int ks = 0; ks < 4; ++ks) {
        s8v a0 = *(const s8v*)(ax0 + ks * 32);
        acc = __builtin_amdgcn_mfma_f32_16x16x32_bf16(a0, bfrag[ks], acc, 0, 0, 0);
      }
    }

    // slow flag after EVERYTHING (incl. sc1 store's LLC ack) has drained
    asm volatile("s_waitcnt vmcnt(0)" ::: "memory");
    if (lane == 0) llc_store4(myflagB, (unsigned)(t + 1));

    rp = wp; wp = (wp == 2) ? 0 : wp + 1;
  }

  // final output row: wait for step T-1, fill h_{T-1} slab, LDS dot.
  if (g == 0) {
    if (w == 0) {
      int m0 = mode_s;
      bool got = false;
      if (m0 == 0) {
        got = wait_flags_fast(srd, polloff, (unsigned)T_);
        if (!got && lane == 0) mode_s = 1;
      }
      if (!got) wait_flags_slow(flagsB, (unsigned)T_);
    }
    __syncthreads();   // also orders last out_dot_lds reads before refill
    fill_slab(h_lds4, mode_s, srd, (unsigned)(rp * HBUFB) + filloffA,
              h_slow + (size_t)rp * HSU64 + slab_u64off, tid);
    __syncthreads();
    out_dot_lds16(h_lds4, T_ - 1, gid, wout_s, bout, out);
  }
}

// ---------------------------------------------------------------------------
extern "C" void kernel_launch(void* const* d_in, const int* in_sizes, int n_in,
                              void* d_out, int out_size, void* d_ws, size_t ws_size,
                              hipStream_t stream) {
  const int*   tokens = (const int*)d_in[0];
  const float* values = (const float*)d_in[1];
  const float* emb    = (const float*)d_in[2];
  const float* W_ih   = (const float*)d_in[3];
  const float* W_hh   = (const float*)d_in[4];
  const float* b_ih   = (const float*)d_in[5];
  const float* b_hh   = (const float*)d_in[6];
  const float* W_out  = (const float*)d_in[7];
  const float* b_out  = (const float*)d_in[8];
  float* out = (float*)d_out;

  char* ws = (char*)d_ws;
  __hip_bfloat16* x_bf = (__hip_bfloat16*)ws;                  // 16 MB
  char* p = ws + (size_t)T_ * B_ * E_ * 2;
  u64*  h_slow  = (u64*)p;                                     // 3 x 128 KB (sc1)
  u32*  barsB   = (u32*)(p + 3 * HBUFB);                       // 4 KB
  u32*  xcc_tab = (u32*)(p + 3 * HBUFB + 4096);                // 512 B
  char* fastbase = p + 3 * HBUFB + 4096 + 512;                 // 384 KB + 4 KB (sc0)

  // zero slow bufs + flags + vote table + fast bufs + fast flags (contiguous)
  hipMemsetAsync(p, 0, (size_t)(3 * HBUFB + 4096 + 512) + FAST_BYTES, stream);

  embed_kernel<<<(B_ * T_ * E_) / 256, 256, 0, stream>>>(tokens, values, emb, x_bf);

  lstm_kernel<<<dim3(NG_ * WPG_), dim3(512), 0, stream>>>(
      W_ih, W_hh, b_ih, b_hh, W_out, b_out, x_bf, h_slow, out, barsB, xcc_tab,
      fastbase);
}

// Round 9
// 2600.178 us; speedup vs baseline: 1.2877x; 1.2877x over previous
//
#include <hip/hip_runtime.h>
#include <hip/hip_bf16.h>

#define B_   128
#define T_   512
#define L_   8
#define E_   128
#define H_   512

// Partition: 8 batch-groups (16 rows each) x 16 WGs = 128 WGs, 256 thr each.
// gid = blockIdx % 8 -> one XCD per group under round-robin dispatch
// (runtime-verified by xcc vote; fallback to agent-scope protocol).
// Fast path: h/flag exchange via MUBUF sc0 on the XCD's coherent L2.
// Producers DUAL-PUBLISH (sc0 + sc1; vmcnt(1) -> fast flag; LLC drain
// deferred behind shadow). wave0-only poll, bounded spin, sleep each iter.
// R5-proven skeleton (2072us): 256 thr, wave=gate, LDS fill, gbuf epilogue.
//
// THIS REVISION (R9): X-LOAD HOIST. The shadow's x-part loads for step t+1
// were issued at their use point; every asm block in the loop has a
// "memory" clobber, so the compiler could NOT hoist them -> ~600-900cy
// L3/HBM stall sat INSIDE the producer's serial chain (after the fast flag,
// before the next poll). Now the 4 s8v loads are ISSUED at the loop head
// (pinned before the poll by the same clobbers) and fly concurrently with
// poll discovery + fill RT; the shadow MFMA finds them resident.
#define NG_   8
#define WPG_  16
#define JW_   32
#define GSTR  132
#define HBUFB 131072                 // bytes per fast h buffer (128 x 1024B)
#define HSU32 32768                  // u32 per slow h buffer
#define HSU64 16384                  // u64 per slow h buffer
#define BARSA_OFF (3 * HBUFB)        // fast flags offset within fast area
#define FAST_BYTES (BARSA_OFF + NG_ * 64 * 4)
#define SPIN_MAX 4096                // bounded fast poll

typedef __attribute__((ext_vector_type(8))) short s8v;      // 8 bf16
typedef __attribute__((ext_vector_type(4))) float f4v;      // MFMA acc
typedef __attribute__((ext_vector_type(4))) unsigned int u32x4;
typedef unsigned long long u64;
typedef unsigned int u32;

__device__ __forceinline__ float bf16u_to_f(unsigned short s) {
  union { unsigned u; float f; } c; c.u = ((unsigned)s) << 16; return c.f;
}
// Agent-scope (sc1): LLC-coherent, bypasses non-coherent per-XCD L2.
__device__ __forceinline__ u64 llc_load8(const void* p) {
  return __hip_atomic_load((const u64*)p, __ATOMIC_RELAXED, __HIP_MEMORY_SCOPE_AGENT);
}
__device__ __forceinline__ unsigned llc_load4(const unsigned* p) {
  return __hip_atomic_load(p, __ATOMIC_RELAXED, __HIP_MEMORY_SCOPE_AGENT);
}
__device__ __forceinline__ void llc_store4(unsigned* p, unsigned v) {
  __hip_atomic_store(p, v, __ATOMIC_RELAXED, __HIP_MEMORY_SCOPE_AGENT);
}
// Fast activations via v_exp_f32 + v_rcp_f32 (~1e-6 abs err)
__device__ __forceinline__ float sigf(float x) {
  return __builtin_amdgcn_rcpf(1.f + __expf(-x));
}
__device__ __forceinline__ float tanh_f(float x) {
  return 1.f - 2.f * __builtin_amdgcn_rcpf(1.f + __expf(2.f * x));
}

// MUBUF sc0 ops (documented gfx950 cache flag for buffer_*).
__device__ __forceinline__ void buf_store_sc0(u32x4 srd, unsigned voff, unsigned v) {
  asm volatile("buffer_store_dword %0, %1, %2, 0 offen sc0"
               :: "v"(v), "v"(voff), "s"(srd) : "memory");
}
__device__ __forceinline__ unsigned buf_load_sc0(u32x4 srd, unsigned voff) {
  unsigned v;
  asm volatile("buffer_load_dword %0, %1, %2, 0 offen sc0\n\ts_waitcnt vmcnt(0)"
               : "=v"(v) : "v"(voff), "s"(srd) : "memory");
  return v;
}

// Wave-0-only polls. Fast: bounded spin, sleep EVERY iteration (anti-storm).
__device__ __forceinline__ bool wait_flags_fast(u32x4 srd, unsigned polloff, unsigned tgt) {
  for (int it = 0; it < SPIN_MAX; ++it) {
    unsigned v = buf_load_sc0(srd, polloff);
    if (__all((int)(v >= tgt))) return true;
    __builtin_amdgcn_s_sleep(1);
  }
  return false;
}
__device__ __forceinline__ void wait_flags_slow(const u32* flags, unsigned tgt) {
  const u32* p = flags + (threadIdx.x & 63);
  while (!__all((int)(llc_load4(p) >= tgt))) __builtin_amdgcn_s_sleep(1);
}

// ---------------------------------------------------------------------------
__global__ void embed_kernel(const int* __restrict__ tokens,
                             const float* __restrict__ values,
                             const float* __restrict__ emb,
                             __hip_bfloat16* __restrict__ x_bf) {
  int idx = blockIdx.x * blockDim.x + threadIdx.x;   // [0, B*T*E)
  int e  = idx & (E_ - 1);
  int bt = idx >> 7;
  int b  = bt >> 9;
  int t  = bt & (T_ - 1);
  const int*   tok = tokens + (size_t)bt * L_;
  const float* val = values + (size_t)bt * L_;
  float acc = 0.f;
#pragma unroll
  for (int l = 0; l < L_; ++l) acc += emb[(size_t)tok[l] * E_ + e] * val[l];
  acc = fmaxf(acc, 0.f);
  x_bf[((size_t)t * B_ + b) * E_ + e] = __float2bfloat16(acc);
}

// ---------------------------------------------------------------------------
// Fill: h_{t-1} group slab (16 rows x 512 bf16 = 16KB) -> LDS, xor-swizzled.
// Thread tid loads 64B contiguous; row = tid>>4. fast: 4x buffer dwordx4 sc0
// + one vmcnt(0). slow: 8x agent u64 loads.
__device__ __forceinline__ void fill_slab(u32x4* __restrict__ h_lds4, int mode,
                                          u32x4 srd, unsigned voffA,
                                          const u64* __restrict__ slow_src,
                                          int tid) {
  u32x4 c0, c1, c2, c3;
  if (mode == 0) {
    asm volatile(
        "buffer_load_dwordx4 %0, %4, %5, 0 offen sc0\n\t"
        "buffer_load_dwordx4 %1, %4, %5, 0 offen offset:16 sc0\n\t"
        "buffer_load_dwordx4 %2, %4, %5, 0 offen offset:32 sc0\n\t"
        "buffer_load_dwordx4 %3, %4, %5, 0 offen offset:48 sc0\n\t"
        "s_waitcnt vmcnt(0)"
        : "=&v"(c0), "=&v"(c1), "=&v"(c2), "=&v"(c3)
        : "v"(voffA), "s"(srd) : "memory");
  } else {
    u64 a, b;
    a = llc_load8(slow_src + 0); b = llc_load8(slow_src + 1);
    c0 = (u32x4){(u32)a, (u32)(a >> 32), (u32)b, (u32)(b >> 32)};
    a = llc_load8(slow_src + 2); b = llc_load8(slow_src + 3);
    c1 = (u32x4){(u32)a, (u32)(a >> 32), (u32)b, (u32)(b >> 32)};
    a = llc_load8(slow_src + 4); b = llc_load8(slow_src + 5);
    c2 = (u32x4){(u32)a, (u32)(a >> 32), (u32)b, (u32)(b >> 32)};
    a = llc_load8(slow_src + 6); b = llc_load8(slow_src + 7);
    c3 = (u32x4){(u32)a, (u32)(a >> 32), (u32)b, (u32)(b >> 32)};
  }
  const int row = tid >> 4;           // 0..15
  const int sw2 = row & 7;
  const int cb  = (tid & 15) * 4;     // 16B-chunk base within row
  u32x4* dst = h_lds4 + (size_t)row * 64;
  dst[(cb + 0) ^ sw2] = c0;
  dst[(cb + 1) ^ sw2] = c1;
  dst[(cb + 2) ^ sw2] = c2;
  dst[(cb + 3) ^ sw2] = c3;
}

// ---------------------------------------------------------------------------
// out[b,t] = W_out . h_t + b_out from the LDS-staged (xor-swizzled) slab.
__device__ __forceinline__ void out_dot_lds16(const u32x4* __restrict__ h_lds4,
                                              int t, int gid,
                                              const float* __restrict__ wout_s,
                                              float bout, float* __restrict__ out) {
  const int um = threadIdx.x >> 4;
  const int uj = threadIdx.x & 15;
  const u64* row = (const u64*)(h_lds4 + (size_t)um * 64);
  const float* wr = wout_s + uj * 32;
  float p = 0.f;
#pragma unroll
  for (int j = 0; j < 4; ++j) {
    int pc = ((uj * 4 + j) ^ (um & 7)) * 2;
    u64 qa = row[pc], qb = row[pc + 1];
    p += bf16u_to_f((unsigned short)(qa      )) * wr[j * 8 + 0];
    p += bf16u_to_f((unsigned short)(qa >> 16)) * wr[j * 8 + 1];
    p += bf16u_to_f((unsigned short)(qa >> 32)) * wr[j * 8 + 2];
    p += bf16u_to_f((unsigned short)(qa >> 48)) * wr[j * 8 + 3];
    p += bf16u_to_f((unsigned short)(qb      )) * wr[j * 8 + 4];
    p += bf16u_to_f((unsigned short)(qb >> 16)) * wr[j * 8 + 5];
    p += bf16u_to_f((unsigned short)(qb >> 32)) * wr[j * 8 + 6];
    p += bf16u_to_f((unsigned short)(qb >> 48)) * wr[j * 8 + 7];
  }
  p += __shfl_down(p, 8, 16);
  p += __shfl_down(p, 4, 16);
  p += __shfl_down(p, 2, 16);
  p += __shfl_down(p, 1, 16);
  if (uj == 0) out[(size_t)(gid * 16 + um) * T_ + t] = p + bout;
}

// ---------------------------------------------------------------------------
__global__ void __launch_bounds__(256, 1)
lstm_kernel(const float* __restrict__ W_ih, const float* __restrict__ W_hh,
            const float* __restrict__ b_ih, const float* __restrict__ b_hh,
            const float* __restrict__ W_out, const float* __restrict__ b_out,
            const __hip_bfloat16* __restrict__ x_bf,
            u64* __restrict__ h_slow,             // 3 * B*H bf16 (zeroed), sc1 copies
            float* __restrict__ out,              // B*T f32
            u32* __restrict__ barsB,              // NG_ x 64 sc1 flags (zeroed)
            u32* __restrict__ xcc_tab,            // 128 slots (zeroed)
            char* __restrict__ fastbase) {        // sc0 area: 3 h bufs + flags (zeroed)
  __shared__ __align__(16) u32x4 h_lds4[16 * 64];  // 16 rows x 64 16B chunks
  __shared__ __align__(16) float gbuf[16][GSTR];   // gates staging
  __shared__ __align__(16) float bias_s[128];
  __shared__ float wout_s[H_];
  __shared__ int   cnt_same_s, bad_grp_s, mode_s;

  const int tid = threadIdx.x;
  const int wg  = blockIdx.x;
  const int gid = wg & (NG_ - 1);     // 0..7  (XCD under round-robin)
  const int g   = wg >> 3;            // 0..15
  const int j0g = g * JW_;

  const int wv   = tid >> 6;          // wave = gate type 0..3
  const int lane = tid & 63;
  const int m16  = lane & 15;
  const int q    = lane >> 4;
  const int sw   = m16 & 7;           // xor-swizzle key

  // SRD over the fast area (num_records=0xFFFFFFFF disables bounds check).
  u32x4 srd;
  {
    unsigned long long ba = (unsigned long long)fastbase;
    srd = (u32x4){(u32)ba, (u32)(ba >> 32) & 0xffffu, 0xffffffffu, 0x00020000u};
  }

  // ---- XCD-placement vote (one-time, agent scope; oracle-failure-safe) ---
  const unsigned xcc = (unsigned)__builtin_amdgcn_s_getreg(20 | (3 << 11));
  if (tid == 0) { cnt_same_s = 0; bad_grp_s = 0; llc_store4(xcc_tab + wg, xcc + 1u); }
  __syncthreads();
  if (tid < 128) {
    const u32* slot = xcc_tab + tid;
    unsigned v = llc_load4(slot);
    while (v == 0u) { __builtin_amdgcn_s_sleep(8); v = llc_load4(slot); }
    if (v == xcc + 1u) atomicAdd(&cnt_same_s, 1);
    else if ((tid & 7) == gid) bad_grp_s = 1;   // a group member is elsewhere
  }
  __syncthreads();
  if (tid == 0) mode_s = ((bad_grp_s == 0) && (cnt_same_s <= 64)) ? 0 : 1;

  // ---- one-time: W fragments -> registers (B operand, 2 N-tiles x 20 K) --
  s8v bfrag[2][20];
#pragma unroll
  for (int nt = 0; nt < 2; ++nt) {
    const int r = wv * H_ + j0g + nt * 16 + m16;        // global gate row
    const float* wih_r = W_ih + (size_t)r * E_;
    const float* whh_r = W_hh + (size_t)r * H_;
#pragma unroll
    for (int ks = 0; ks < 20; ++ks) {
      s8v v;
#pragma unroll
      for (int i = 0; i < 8; ++i) {
        int k = ks * 32 + q * 8 + i;
        float w = (k < E_) ? wih_r[k] : whh_r[k - E_];
        __hip_bfloat16 hb = __float2bfloat16(w);
        v[i] = *(short*)&hb;
      }
      bfrag[nt][ks] = v;
    }
  }
  if (tid < 128) {
    int gt = tid >> 5, jl = tid & 31;
    int r = gt * H_ + j0g + jl;
    bias_s[tid] = b_ih[r] + b_hh[r];
  }
  if (g == 0) for (int i = tid; i < H_; i += 256) wout_s[i] = W_out[i];

  // ---- per-step identities ----------------------------------------------
  const int um = tid >> 4;            // update/fill/out row (0..15)
  const int jb = (tid & 15) * 2;      // update: 2 hidden units
  const int ub = gid * 16 + um;       // global batch row
  float cst[2] = {0.f, 0.f};
  const float bout = b_out[0];
  u32* h_slow32 = (u32*)h_slow;
  u32* flagsB   = barsB + gid * 64;
  u32* myflagB  = flagsB + (g << 2) + wv;
  const unsigned flagAoff   = (unsigned)(BARSA_OFF + (gid * 64 + (g << 2) + wv) * 4);
  const unsigned polloff    = (unsigned)(BARSA_OFF + (gid * 64 + lane) * 4);
  const unsigned filloffA   = (unsigned)((gid * 16 + (tid >> 4)) * 1024 + (tid & 15) * 64);
  const unsigned slab_u64off = (unsigned)(gid * 16 * 128 + tid * 8);

  int rp = 2, wp = 0;                 // h_{-1}=zeros in buf2; h_t -> buf t%3
  f4v acc[2];

  // prologue: x-part of step 0 (M=16: single A-tile)
  {
    const __hip_bfloat16* ax0 = x_bf + (size_t)(gid * 16 + m16) * E_ + q * 8;
    f4v z = {0.f, 0.f, 0.f, 0.f};
    acc[0] = z; acc[1] = z;
#pragma unroll
    for (int ks = 0; ks < 4; ++ks) {
      s8v a0 = *(const s8v*)(ax0 + ks * 32);
#pragma unroll
      for (int nt = 0; nt < 2; ++nt)
        acc[nt] = __builtin_amdgcn_mfma_f32_16x16x32_bf16(a0, bfrag[nt][ks], acc[nt], 0, 0, 0);
    }
  }
  __syncthreads();   // bias/wout/mode_s ready

  for (int t = 0; t < T_; ++t) {
    // ---- R9 HOIST: issue x loads for step t+1 NOW (fly under poll+fill) -
    // The asm "memory" clobbers below pin these issues BEFORE the poll;
    // first use is in the shadow MFMA, so no waitcnt until then.
    s8v xa[4];
    if (t + 1 < T_) {
      const __hip_bfloat16* ax0 = x_bf + (size_t)(t + 1) * B_ * E_
                                       + (size_t)(gid * 16 + m16) * E_ + q * 8;
#pragma unroll
      for (int ks = 0; ks < 4; ++ks) xa[ks] = *(const s8v*)(ax0 + ks * 32);
    }

    // ---- wave 0 waits for step t-1 producers (bounded fast + fallback) --
    if (wv == 0) {
      int m0 = mode_s;
      bool got = false;
      if (m0 == 0) {
        got = wait_flags_fast(srd, polloff, (unsigned)t);
        if (!got && lane == 0) mode_s = 1;   // permanent fallback
      }
      if (!got) wait_flags_slow(flagsB, (unsigned)t);
    }
    __syncthreads();   // release; also orders shadow h_lds reads before fill
    const int mode = mode_s;

    // ---- cooperative fill: h_{t-1} group slab -> LDS --------------------
    fill_slab(h_lds4, mode, srd, (unsigned)(rp * HBUFB) + filloffA,
              h_slow + (size_t)rp * HSU64 + slab_u64off, tid);
    __syncthreads();   // fill complete

    // ---- h-part MFMAs (K=512 from LDS; B from registers) ----------------
    {
      const s8v* arow = (const s8v*)(h_lds4 + (size_t)m16 * 64);
#pragma unroll
      for (int ks4 = 0; ks4 < 16; ++ks4) {
        s8v a0 = arow[(ks4 * 4 + q) ^ sw];
#pragma unroll
        for (int nt = 0; nt < 2; ++nt)
          acc[nt] = __builtin_amdgcn_mfma_f32_16x16x32_bf16(a0, bfrag[nt][4 + ks4], acc[nt], 0, 0, 0);
      }
    }

    // ---- stage gates to LDS (D: row=quad*4+r, col=m16) ------------------
#pragma unroll
    for (int nt = 0; nt < 2; ++nt)
#pragma unroll
      for (int r = 0; r < 4; ++r)
        gbuf[q * 4 + r][wv * 32 + nt * 16 + m16] = acc[nt][r];
    __syncthreads();   // gates ready

    // ---- CRITICAL PATH: pointwise -> dual h store -> fast flag ----------
    {
      const float* gr = &gbuf[um][0];
      float gi0 = gr[jb],      gi1 = gr[jb + 1];
      float gf0 = gr[32 + jb], gf1 = gr[33 + jb];
      float gg0 = gr[64 + jb], gg1 = gr[65 + jb];
      float go0 = gr[96 + jb], go1 = gr[97 + jb];
      float si0 = sigf(gi0 + bias_s[jb]);
      float si1 = sigf(gi1 + bias_s[jb + 1]);
      float sf0 = sigf(gf0 + bias_s[32 + jb]);
      float sf1 = sigf(gf1 + bias_s[33 + jb]);
      float tg0 = tanh_f(gg0 + bias_s[64 + jb]);
      float tg1 = tanh_f(gg1 + bias_s[65 + jb]);
      float so0 = sigf(go0 + bias_s[96 + jb]);
      float so1 = sigf(go1 + bias_s[97 + jb]);
      cst[0] = sf0 * cst[0] + si0 * tg0;
      cst[1] = sf1 * cst[1] + si1 * tg1;
      float h0 = so0 * tanh_f(cst[0]);
      float h1 = so1 * tanh_f(cst[1]);
      __hip_bfloat16 hb0 = __float2bfloat16(h0);
      __hip_bfloat16 hb1 = __float2bfloat16(h1);
      u32 w = (u32)(*(unsigned short*)&hb0) | ((u32)(*(unsigned short*)&hb1) << 16);
      // op1: fast copy (sc0, acked at local L2)
      buf_store_sc0(srd, (unsigned)(wp * HBUFB)
                         + (unsigned)(ub * 1024 + (g * 16 + (tid & 15)) * 4), w);
      // op2: slow copy (sc1, acked at LLC) -- drain deferred to shadow end
      llc_store4(h_slow32 + (size_t)wp * HSU32
                          + (size_t)(ub * 256 + g * 16 + (tid & 15)), w);
      // fast flag after op1 only (oldest outstanding)
      asm volatile("s_waitcnt vmcnt(1)" ::: "memory");
      if (lane == 0) buf_store_sc0(srd, flagAoff, (unsigned)(t + 1));
    }

    // ---- poll-shadow work (other WGs are polling/filling) ---------------
    if (g == 0 && t > 0)               // h_{t-1} still staged in LDS
      out_dot_lds16(h_lds4, t - 1, gid, wout_s, bout, out);

    if (t + 1 < T_) {                  // x-part of step t+1, loads pre-issued
      f4v z = {0.f, 0.f, 0.f, 0.f};
      acc[0] = z; acc[1] = z;
#pragma unroll
      for (int ks = 0; ks < 4; ++ks) {
#pragma unroll
        for (int nt = 0; nt < 2; ++nt)
          acc[nt] = __builtin_amdgcn_mfma_f32_16x16x32_bf16(xa[ks], bfrag[nt][ks], acc[nt], 0, 0, 0);
      }
    }

    // slow flag after EVERYTHING (incl. sc1 store's LLC ack) has drained
    asm volatile("s_waitcnt vmcnt(0)" ::: "memory");
    if (lane == 0) llc_store4(myflagB, (unsigned)(t + 1));

    rp = wp; wp = (wp == 2) ? 0 : wp + 1;
  }

  // final output row: wait for step T-1, fill h_{T-1} slab, LDS dot.
  if (g == 0) {
    if (wv == 0) {
      int m0 = mode_s;
      bool got = false;
      if (m0 == 0) {
        got = wait_flags_fast(srd, polloff, (unsigned)T_);
        if (!got && lane == 0) mode_s = 1;
      }
      if (!got) wait_flags_slow(flagsB, (unsigned)T_);
    }
    __syncthreads();   // also orders last out_dot_lds reads before refill
    fill_slab(h_lds4, mode_s, srd, (unsigned)((T_ - 1) % 3 * HBUFB) + filloffA,
              h_slow + (size_t)((T_ - 1) % 3) * HSU64 + slab_u64off, tid);
    __syncthreads();
    out_dot_lds16(h_lds4, T_ - 1, gid, wout_s, bout, out);
  }
}

// ---------------------------------------------------------------------------
extern "C" void kernel_launch(void* const* d_in, const int* in_sizes, int n_in,
                              void* d_out, int out_size, void* d_ws, size_t ws_size,
                              hipStream_t stream) {
  const int*   tokens = (const int*)d_in[0];
  const float* values = (const float*)d_in[1];
  const float* emb    = (const float*)d_in[2];
  const float* W_ih   = (const float*)d_in[3];
  const float* W_hh   = (const float*)d_in[4];
  const float* b_ih   = (const float*)d_in[5];
  const float* b_hh   = (const float*)d_in[6];
  const float* W_out  = (const float*)d_in[7];
  const float* b_out  = (const float*)d_in[8];
  float* out = (float*)d_out;

  char* ws = (char*)d_ws;
  __hip_bfloat16* x_bf = (__hip_bfloat16*)ws;                  // 16 MB
  char* p = ws + (size_t)T_ * B_ * E_ * 2;
  u64*  h_slow  = (u64*)p;                                     // 3 x 128 KB (sc1)
  u32*  barsB   = (u32*)(p + 3 * HBUFB);                       // 2 KB
  u32*  xcc_tab = (u32*)(p + 3 * HBUFB + 2048);                // 512 B
  char* fastbase = p + 3 * HBUFB + 2048 + 512;                 // 384 KB + 2 KB (sc0)

  // zero slow bufs + flags + vote table + fast bufs + fast flags (contiguous)
  hipMemsetAsync(p, 0, (size_t)(3 * HBUFB + 2048 + 512) + FAST_BYTES, stream);

  embed_kernel<<<(B_ * T_ * E_) / 256, 256, 0, stream>>>(tokens, values, emb, x_bf);

  lstm_kernel<<<dim3(NG_ * WPG_), dim3(256), 0, stream>>>(
      W_ih, W_hh, b_ih, b_hh, W_out, b_out, x_bf, h_slow, out, barsB, xcc_tab,
      fastbase);
}